// Round 1
// baseline (5342.086 us; speedup 1.0000x reference)
//
#include <hip/hip_runtime.h>
#include <hip/hip_fp16.h>

#define Bb 128
#define Tt 1024
#define Dd 512
#define Hh 512
#define NBX 8     // batch tiles of 16
#define NBY 32    // hid tiles of 16
#define BH (Bb*Hh)

typedef _Float16 f16;
typedef unsigned long long u64;
typedef __attribute__((ext_vector_type(8))) _Float16 f16x8;
typedef __attribute__((ext_vector_type(4))) float fx4;

__device__ __forceinline__ float sigm(float x)  { return 1.f / (1.f + __expf(-x)); }
__device__ __forceinline__ float tanh_f(float x){ return 2.f / (1.f + __expf(-2.f * x)) - 1.f; }

// zero hbuf (2 x 128x512 f16 = 65536 uints) and flags (8x1024 ints)
__global__ void k_init(unsigned* hb, unsigned* fl) {
  int i = blockIdx.x * 256 + threadIdx.x;      // grid 256 -> 65536 threads
  hb[i] = 0u;
  if (i < NBX * Tt) fl[i] = 0u;
}

// Wc[g][k] fp16: k<512 -> W_ih[g][k], else W_hh[g][k-512]
__global__ void k_convw(const float* __restrict__ Wih, const float* __restrict__ Whh,
                        f16* __restrict__ Wc) {
  int i = blockIdx.x * 256 + threadIdx.x;      // 2048*1024
  int g = i >> 10, k = i & 1023;
  float v = (k < Dd) ? Wih[g * Dd + k] : Whh[g * Hh + (k - Dd)];
  Wc[i] = (f16)v;
}

// X fp32 -> fp16, 4/thread
__global__ void k_convx(const float* __restrict__ X, f16* __restrict__ Xh) {
  long i = ((long)blockIdx.x * 256 + threadIdx.x) * 4;
  float4 v = *(const float4*)(X + i);
  Xh[i] = (f16)v.x; Xh[i+1] = (f16)v.y; Xh[i+2] = (f16)v.z; Xh[i+3] = (f16)v.w;
}

// Persistent LSTM kernel. Grid (8,32), block 256 = 4 waves.
// Block tile: 16 batches (bx) x 64 gate rows (= 16 hid x 4 types, by).
// K=1024 (512 x | 512 h) split across 4 waves (256 K each): waves 0,1 = x-part,
// waves 2,3 = h-part. W fragments live in 128 VGPRs/wave for the whole kernel.
//
// Per-step sync protocol (NO threadfence — fine-grained agent-coherent ops):
//   writer: h packed 2xf16 -> u32, __hip_atomic_store RELAXED/AGENT (sc0 sc1,
//           write-through past non-coherent L2). __syncthreads drains vmcnt(0)
//           per wave before s_barrier => all h stores agent-visible. Then tid0
//           does a RELAXED fetch_add on the per-(bx,t) counter.
//   reader: tid0 polls the counter with RELAXED/AGENT loads; after the
//           barrier, h is read with __hip_atomic_load u64 RELAXED/AGENT
//           (sc0 sc1 => bypasses stale L1/L2). No buffer_wbl2/buffer_inv
//           anywhere in the loop; L2 stays warm for the Xh stream.
template<bool XPRE>
__global__ __launch_bounds__(256, 1) void k_rnn(
    const float* __restrict__ X, const f16* __restrict__ Xh,
    const f16* __restrict__ Wc,
    f16* __restrict__ hbuf,            // [2][B*H]
    int* __restrict__ flags,           // [NBX][Tt]
    const int* __restrict__ lens,
    const float* __restrict__ bih, const float* __restrict__ bhh,
    float* __restrict__ out)
{
  const int bx   = blockIdx.x;         // batch tile
  const int by   = blockIdx.y;         // hid tile
  const int tid  = threadIdx.x;
  const int wave = tid >> 6;
  const int lane = tid & 63;
  const int ml   = lane & 15;
  const int quad = lane >> 4;
  const int b0   = bx * 16;
  const int hid0 = by * 16;

  __shared__ float pp[4][4][16][16];   // [wave][type][b][hid] partials, 16 KB

  const int mlen = lens[b0];           // group max length (sorted descending)

  // cell ownership: thread tid <-> (b = tid>>4, hid = tid&15)
  const int cb  = tid >> 4, chd = tid & 15;
  const int myb = b0 + cb,  myh = hid0 + chd;
  const int mylen = lens[myb];
  const float bi_i = bih[myh]        + bhh[myh];
  const float bi_f = bih[Hh + myh]   + bhh[Hh + myh];
  const float bi_g = bih[2*Hh + myh] + bhh[2*Hh + myh];
  const float bi_o = bih[3*Hh + myh] + bhh[3*Hh + myh];
  float c_reg = 0.f, h_reg = 0.f;

  // preload this wave's W fragments: rows = tj*512 + hid0 + ml,
  // k = wave*256 + kc*32 + quad*8  -> 8 kc x 4 tj x 4 VGPRs = 128 VGPRs
  f16x8 wfr[8][4];
  {
    const f16* wp = Wc + (long)(hid0 + ml) * 1024 + wave * 256 + quad * 8;
    #pragma unroll
    for (int kc = 0; kc < 8; ++kc)
      #pragma unroll
      for (int tj = 0; tj < 4; ++tj)
        wfr[kc][tj] = *(const f16x8*)(wp + (long)tj * Hh * 1024 + kc * 32);
  }

  int* gflag = flags + bx * Tt;
  const f16*   xp  = Xh + ((long)(b0 + ml) * Tt) * Dd + wave * 256 + quad * 8;
  const float* xpf = X  + ((long)(b0 + ml) * Tt) * Dd + wave * 256 + quad * 8;

  for (int t = 0; t < mlen; ++t) {
    fx4 zero = {0.f, 0.f, 0.f, 0.f};
    fx4 acc[4] = {zero, zero, zero, zero};

    if (wave < 2) {
      // x-part: no dependency on other blocks' h -> runs before the flag wait
      #pragma unroll
      for (int kc = 0; kc < 8; ++kc) {
        f16x8 a;
        if (XPRE) {
          a = *(const f16x8*)(xp + (long)t * Dd + kc * 32);
        } else {
          float4 x0 = *(const float4*)(xpf + (long)t * Dd + kc * 32);
          float4 x1 = *(const float4*)(xpf + (long)t * Dd + kc * 32 + 4);
          a[0]=(f16)x0.x; a[1]=(f16)x0.y; a[2]=(f16)x0.z; a[3]=(f16)x0.w;
          a[4]=(f16)x1.x; a[5]=(f16)x1.y; a[6]=(f16)x1.z; a[7]=(f16)x1.w;
        }
        #pragma unroll
        for (int tj = 0; tj < 4; ++tj)
          acc[tj] = __builtin_amdgcn_mfma_f32_16x16x32_f16(a, wfr[kc][tj], acc[tj], 0, 0, 0);
      }
      #pragma unroll
      for (int tj = 0; tj < 4; ++tj)
        #pragma unroll
        for (int r = 0; r < 4; ++r)
          pp[wave][tj][quad * 4 + r][ml] = acc[tj][r];
    }

    // wait for all 32 group blocks to have published h_{t-1}
    if (tid == 0 && t > 0) {
      while (__hip_atomic_load(gflag + (t - 1), __ATOMIC_RELAXED,
                               __HIP_MEMORY_SCOPE_AGENT) < NBY)
        __builtin_amdgcn_s_sleep(1);
    }
    __syncthreads();
    // NOTE: no acquire fence — h loads below are agent-coherent (sc0 sc1)

    if (wave >= 2) {
      const u64* hp = (const u64*)(hbuf + (long)((t + 1) & 1) * BH
                    + (long)(b0 + ml) * Hh + (wave - 2) * 256 + quad * 8);
      #pragma unroll
      for (int kc = 0; kc < 8; ++kc) {
        union { f16x8 v; u64 q[2]; } ua;
        ua.q[0] = __hip_atomic_load(hp + kc * 8,     __ATOMIC_RELAXED,
                                    __HIP_MEMORY_SCOPE_AGENT);
        ua.q[1] = __hip_atomic_load(hp + kc * 8 + 1, __ATOMIC_RELAXED,
                                    __HIP_MEMORY_SCOPE_AGENT);
        f16x8 a = ua.v;
        #pragma unroll
        for (int tj = 0; tj < 4; ++tj)
          acc[tj] = __builtin_amdgcn_mfma_f32_16x16x32_f16(a, wfr[kc][tj], acc[tj], 0, 0, 0);
      }
      #pragma unroll
      for (int tj = 0; tj < 4; ++tj)
        #pragma unroll
        for (int r = 0; r < 4; ++r)
          pp[wave][tj][quad * 4 + r][ml] = acc[tj][r];
    }
    __syncthreads();

    // reduce 4 partials + cell update (lane-local: all 4 gate types in-thread)
    {
      float g0 = pp[0][0][cb][chd] + pp[1][0][cb][chd] + pp[2][0][cb][chd] + pp[3][0][cb][chd];
      float g1 = pp[0][1][cb][chd] + pp[1][1][cb][chd] + pp[2][1][cb][chd] + pp[3][1][cb][chd];
      float g2 = pp[0][2][cb][chd] + pp[1][2][cb][chd] + pp[2][2][cb][chd] + pp[3][2][cb][chd];
      float g3 = pp[0][3][cb][chd] + pp[1][3][cb][chd] + pp[2][3][cb][chd] + pp[3][3][cb][chd];
      long oidx = ((long)myb * Tt + t) * Hh + myh;
      if (t < mylen) {
        float iv = sigm(g0 + bi_i);
        float fv = sigm(g1 + bi_f);
        float gv = tanh_f(g2 + bi_g);
        float ov = sigm(g3 + bi_o);
        c_reg = fv * c_reg + iv * gv;
        h_reg = ov * tanh_f(c_reg);
        __builtin_nontemporal_store(h_reg, out + oidx);
      } else {
        __builtin_nontemporal_store(0.f, out + oidx);
      }
      // publish h: pack 2 x f16 -> u32, agent-coherent store (sc0 sc1)
      f16 hf = (f16)h_reg;
      unsigned hu = (unsigned)__builtin_bit_cast(unsigned short, hf);
      int nb = __shfl_down((int)hu, 1);   // neighbor (tid+1, same wave)
      if (!(tid & 1)) {
        unsigned v = hu | ((unsigned)nb << 16);
        unsigned* dst = (unsigned*)(hbuf + (long)(t & 1) * BH
                                  + (long)myb * Hh + myh);
        __hip_atomic_store(dst, v, __ATOMIC_RELAXED, __HIP_MEMORY_SCOPE_AGENT);
      }
    }
    __syncthreads();   // drains vmcnt(0) per wave => h stores agent-visible

    if (tid == 0) {
      // release is provided by the barrier's vmcnt drain (stores were sc0/sc1)
      __hip_atomic_fetch_add(gflag + t, 1, __ATOMIC_RELAXED,
                             __HIP_MEMORY_SCOPE_AGENT);
    }
  }

  // zero-fill output tail for t >= group max length
  for (int t = mlen; t < Tt; ++t)
    __builtin_nontemporal_store(0.f, out + ((long)myb * Tt + t) * Hh + myh);

  // final h, c
  long base = (long)Bb * Tt * Hh;
  out[base + (long)myb * Hh + myh]      = h_reg;
  out[base + BH + (long)myb * Hh + myh] = c_reg;
}

extern "C" void kernel_launch(void* const* d_in, const int* in_sizes, int n_in,
                              void* d_out, int out_size, void* d_ws, size_t ws_size,
                              hipStream_t stream) {
  const float* X   = (const float*)d_in[0];
  const int*  lens = (const int*)d_in[1];
  const float* Wih = (const float*)d_in[2];
  const float* Whh = (const float*)d_in[3];
  const float* bih = (const float*)d_in[4];
  const float* bhh = (const float*)d_in[5];
  float* out = (float*)d_out;

  char* w = (char*)d_ws;
  f16* hbuf   = (f16*)(w);                        // 256 KB
  int* flags  = (int*)(w + (1u << 18));           // 32 KB
  f16* Wc     = (f16*)(w + (1u << 19));           // 4 MB
  f16* Xh     = (f16*)(w + (9u << 19));           // 128 MB
  size_t need_full = (size_t)(9u << 19) + (size_t)Bb * Tt * Dd * sizeof(f16);
  bool xpre = ws_size >= need_full;

  k_init <<<256,  256, 0, stream>>>((unsigned*)hbuf, (unsigned*)flags);
  k_convw<<<8192, 256, 0, stream>>>(Wih, Whh, Wc);
  if (xpre) k_convx<<<65536, 256, 0, stream>>>(X, Xh);

  dim3 grid(NBX, NBY);
  if (xpre)
    k_rnn<true ><<<grid, 256, 0, stream>>>(X, Xh, Wc, hbuf, flags, lens, bih, bhh, out);
  else
    k_rnn<false><<<grid, 256, 0, stream>>>(X, Xh, Wc, hbuf, flags, lens, bih, bhh, out);
}

// Round 2
// 3880.608 us; speedup vs baseline: 1.3766x; 1.3766x over previous
//
#include <hip/hip_runtime.h>
#include <hip/hip_fp16.h>

#define Bb 128
#define Tt 1024
#define Dd 512
#define Hh 512
#define NBX 8     // batch tiles of 16
#define NBY 32    // hid tiles of 16
#define BH (Bb*Hh)

typedef _Float16 f16;
typedef unsigned long long u64;
typedef __attribute__((ext_vector_type(8))) _Float16 f16x8;
typedef __attribute__((ext_vector_type(4))) float fx4;

__device__ __forceinline__ float sigm(float x)  { return 1.f / (1.f + __expf(-x)); }
__device__ __forceinline__ float tanh_f(float x){ return 2.f / (1.f + __expf(-2.f * x)) - 1.f; }

// zero hbuf (2 x 128x512 f16 = 65536 uints) and flags (8x1024 ints region)
__global__ void k_init(unsigned* hb, unsigned* fl) {
  int i = blockIdx.x * 256 + threadIdx.x;      // grid 256 -> 65536 threads
  hb[i] = 0u;
  if (i < NBX * Tt) fl[i] = 0u;
}

// Wc[g][k] fp16: k<512 -> W_ih[g][k], else W_hh[g][k-512]
__global__ void k_convw(const float* __restrict__ Wih, const float* __restrict__ Whh,
                        f16* __restrict__ Wc) {
  int i = blockIdx.x * 256 + threadIdx.x;      // 2048*1024
  int g = i >> 10, k = i & 1023;
  float v = (k < Dd) ? Wih[g * Dd + k] : Whh[g * Hh + (k - Dd)];
  Wc[i] = (f16)v;
}

// X fp32 -> fp16, 4/thread
__global__ void k_convx(const float* __restrict__ X, f16* __restrict__ Xh) {
  long i = ((long)blockIdx.x * 256 + threadIdx.x) * 4;
  float4 v = *(const float4*)(X + i);
  Xh[i] = (f16)v.x; Xh[i+1] = (f16)v.y; Xh[i+2] = (f16)v.z; Xh[i+3] = (f16)v.w;
}

// Persistent LSTM kernel. Grid (8,32), block 256 = 4 waves.
// Block tile: 16 batches (bx) x 64 gate rows (= 16 hid x 4 types, by).
// K split: EVERY wave handles 128 K of x (pre-wait, acc carried in registers
// across the poll) + 128 K of h (post-wait). W fragments: 128 VGPRs/wave.
//
// Sync protocol (per-block monotonic flags, no RMW, no fences):
//   writer: h packed 2xf16 -> u32 sc0/sc1 store; __syncthreads drains vmcnt
//           per wave => h agent-visible; tid0 STORES flags[bx*32+by] = t+1.
//   reader: each wave polls all 32 flags in parallel (lane&31) with
//           RELAXED/AGENT loads until __all(flag >= t); no barrier needed
//           between poll and h loads. h loads are u64 RELAXED/AGENT
//           (sc0 sc1, bypass stale L1/L2). No buffer_wbl2/inv anywhere.
//   'out' HBM stores issued AFTER the flag publish: their ack latency
//   overlaps the next step's x-part + wait instead of the release drain.
template<bool XPRE>
__global__ __launch_bounds__(256, 1) void k_rnn(
    const float* __restrict__ X, const f16* __restrict__ Xh,
    const f16* __restrict__ Wc,
    f16* __restrict__ hbuf,            // [2][B*H]
    int* __restrict__ flags,           // [NBX][32] monotonic
    const int* __restrict__ lens,
    const float* __restrict__ bih, const float* __restrict__ bhh,
    float* __restrict__ out)
{
  const int bx   = blockIdx.x;         // batch tile
  const int by   = blockIdx.y;         // hid tile
  const int tid  = threadIdx.x;
  const int wave = tid >> 6;
  const int lane = tid & 63;
  const int ml   = lane & 15;
  const int quad = lane >> 4;
  const int b0   = bx * 16;
  const int hid0 = by * 16;

  __shared__ float pp[4][4][16][16];   // [wave][type][b][hid] partials, 16 KB

  const int mlen = lens[b0];           // group max length (sorted descending)

  // cell ownership: thread tid <-> (b = tid>>4, hid = tid&15)
  const int cb  = tid >> 4, chd = tid & 15;
  const int myb = b0 + cb,  myh = hid0 + chd;
  const int mylen = lens[myb];
  const float bi_i = bih[myh]        + bhh[myh];
  const float bi_f = bih[Hh + myh]   + bhh[Hh + myh];
  const float bi_g = bih[2*Hh + myh] + bhh[2*Hh + myh];
  const float bi_o = bih[3*Hh + myh] + bhh[3*Hh + myh];
  float c_reg = 0.f, h_reg = 0.f;

  // preload W fragments: rows = tj*512 + hid0 + ml.
  // kc 0..3: x-part, k = wave*128 + kc*32 + quad*8
  // kc 4..7: h-part, k = 512 + wave*128 + (kc-4)*32 + quad*8
  f16x8 wfr[8][4];
  {
    const f16* wp = Wc + (long)(hid0 + ml) * 1024 + quad * 8;
    #pragma unroll
    for (int kc = 0; kc < 4; ++kc)
      #pragma unroll
      for (int tj = 0; tj < 4; ++tj) {
        wfr[kc][tj]     = *(const f16x8*)(wp + (long)tj * Hh * 1024 + wave * 128 + kc * 32);
        wfr[kc + 4][tj] = *(const f16x8*)(wp + (long)tj * Hh * 1024 + 512 + wave * 128 + kc * 32);
      }
  }

  int* gflag = flags + bx * 32;
  const f16*   xp  = Xh + ((long)(b0 + ml) * Tt) * Dd + wave * 128 + quad * 8;
  const float* xpf = X  + ((long)(b0 + ml) * Tt) * Dd + wave * 128 + quad * 8;

  for (int t = 0; t < mlen; ++t) {
    fx4 zero = {0.f, 0.f, 0.f, 0.f};
    fx4 acc[4] = {zero, zero, zero, zero};

    // x-part: 128 K per wave, no cross-block dependency -> pre-wait
    #pragma unroll
    for (int kc = 0; kc < 4; ++kc) {
      f16x8 a;
      if (XPRE) {
        a = *(const f16x8*)(xp + (long)t * Dd + kc * 32);
      } else {
        float4 x0 = *(const float4*)(xpf + (long)t * Dd + kc * 32);
        float4 x1 = *(const float4*)(xpf + (long)t * Dd + kc * 32 + 4);
        a[0]=(f16)x0.x; a[1]=(f16)x0.y; a[2]=(f16)x0.z; a[3]=(f16)x0.w;
        a[4]=(f16)x1.x; a[5]=(f16)x1.y; a[6]=(f16)x1.z; a[7]=(f16)x1.w;
      }
      #pragma unroll
      for (int tj = 0; tj < 4; ++tj)
        acc[tj] = __builtin_amdgcn_mfma_f32_16x16x32_f16(a, wfr[kc][tj], acc[tj], 0, 0, 0);
    }

    // per-wave wait: all 32 group blocks published h_{t-1}
    if (t > 0) {
      const int* fp = gflag + (lane & 31);
      while (true) {
        int v = __hip_atomic_load(fp, __ATOMIC_RELAXED, __HIP_MEMORY_SCOPE_AGENT);
        if (__all(v >= t)) break;
        __builtin_amdgcn_s_sleep(1);
      }
    }

    // h-part: 128 K per wave, agent-coherent loads
    {
      const u64* hp = (const u64*)(hbuf + (long)((t + 1) & 1) * BH
                    + (long)(b0 + ml) * Hh + wave * 128 + quad * 8);
      #pragma unroll
      for (int kc = 0; kc < 4; ++kc) {
        union { f16x8 v; u64 q[2]; } ua;
        ua.q[0] = __hip_atomic_load(hp + kc * 8,     __ATOMIC_RELAXED,
                                    __HIP_MEMORY_SCOPE_AGENT);
        ua.q[1] = __hip_atomic_load(hp + kc * 8 + 1, __ATOMIC_RELAXED,
                                    __HIP_MEMORY_SCOPE_AGENT);
        #pragma unroll
        for (int tj = 0; tj < 4; ++tj)
          acc[tj] = __builtin_amdgcn_mfma_f32_16x16x32_f16(ua.v, wfr[kc + 4][tj], acc[tj], 0, 0, 0);
      }
    }

    #pragma unroll
    for (int tj = 0; tj < 4; ++tj)
      #pragma unroll
      for (int r = 0; r < 4; ++r)
        pp[wave][tj][quad * 4 + r][ml] = acc[tj][r];
    __syncthreads();

    // reduce 4 partials + cell update (lane-local: all 4 gate types in-thread)
    float out_val;
    {
      float g0 = pp[0][0][cb][chd] + pp[1][0][cb][chd] + pp[2][0][cb][chd] + pp[3][0][cb][chd];
      float g1 = pp[0][1][cb][chd] + pp[1][1][cb][chd] + pp[2][1][cb][chd] + pp[3][1][cb][chd];
      float g2 = pp[0][2][cb][chd] + pp[1][2][cb][chd] + pp[2][2][cb][chd] + pp[3][2][cb][chd];
      float g3 = pp[0][3][cb][chd] + pp[1][3][cb][chd] + pp[2][3][cb][chd] + pp[3][3][cb][chd];
      if (t < mylen) {
        float iv = sigm(g0 + bi_i);
        float fv = sigm(g1 + bi_f);
        float gv = tanh_f(g2 + bi_g);
        float ov = sigm(g3 + bi_o);
        c_reg = fv * c_reg + iv * gv;
        h_reg = ov * tanh_f(c_reg);
        out_val = h_reg;
      } else {
        out_val = 0.f;
      }
      // publish h: pack 2 x f16 -> u32, agent-coherent store (sc0 sc1)
      f16 hf = (f16)h_reg;
      unsigned hu = (unsigned)__builtin_bit_cast(unsigned short, hf);
      int nb = __shfl_down((int)hu, 1);   // neighbor (tid+1, same wave)
      if (!(tid & 1)) {
        unsigned v = hu | ((unsigned)nb << 16);
        unsigned* dst = (unsigned*)(hbuf + (long)(t & 1) * BH
                                  + (long)myb * Hh + myh);
        __hip_atomic_store(dst, v, __ATOMIC_RELAXED, __HIP_MEMORY_SCOPE_AGENT);
      }
    }
    __syncthreads();   // drains vmcnt(0) per wave => h stores agent-visible

    if (tid == 0)      // per-block flag: plain agent store, no RMW
      __hip_atomic_store(gflag + by, t + 1, __ATOMIC_RELAXED,
                         __HIP_MEMORY_SCOPE_AGENT);

    // out store AFTER publish: ack overlaps next step's x-part + wait
    __builtin_nontemporal_store(out_val, out + ((long)myb * Tt + t) * Hh + myh);
  }

  // zero-fill output tail for t >= group max length
  for (int t = mlen; t < Tt; ++t)
    __builtin_nontemporal_store(0.f, out + ((long)myb * Tt + t) * Hh + myh);

  // final h, c
  long base = (long)Bb * Tt * Hh;
  out[base + (long)myb * Hh + myh]      = h_reg;
  out[base + BH + (long)myb * Hh + myh] = c_reg;
}

extern "C" void kernel_launch(void* const* d_in, const int* in_sizes, int n_in,
                              void* d_out, int out_size, void* d_ws, size_t ws_size,
                              hipStream_t stream) {
  const float* X   = (const float*)d_in[0];
  const int*  lens = (const int*)d_in[1];
  const float* Wih = (const float*)d_in[2];
  const float* Whh = (const float*)d_in[3];
  const float* bih = (const float*)d_in[4];
  const float* bhh = (const float*)d_in[5];
  float* out = (float*)d_out;

  char* w = (char*)d_ws;
  f16* hbuf   = (f16*)(w);                        // 256 KB
  int* flags  = (int*)(w + (1u << 18));           // 32 KB
  f16* Wc     = (f16*)(w + (1u << 19));           // 4 MB
  f16* Xh     = (f16*)(w + (9u << 19));           // 128 MB
  size_t need_full = (size_t)(9u << 19) + (size_t)Bb * Tt * Dd * sizeof(f16);
  bool xpre = ws_size >= need_full;

  k_init <<<256,  256, 0, stream>>>((unsigned*)hbuf, (unsigned*)flags);
  k_convw<<<8192, 256, 0, stream>>>(Wih, Whh, Wc);
  if (xpre) k_convx<<<65536, 256, 0, stream>>>(X, Xh);

  dim3 grid(NBX, NBY);
  if (xpre)
    k_rnn<true ><<<grid, 256, 0, stream>>>(X, Xh, Wc, hbuf, flags, lens, bih, bhh, out);
  else
    k_rnn<false><<<grid, 256, 0, stream>>>(X, Xh, Wc, hbuf, flags, lens, bih, bhh, out);
}